// Round 3
// baseline (618.930 us; speedup 1.0000x reference)
//
#include <hip/hip_runtime.h>
#include <hip/hip_bf16.h>

#define N_NODES 100000
#define D 128
#define EPT 250000
#define NT 7
#define NSEG (NT * N_NODES)   // 700000
#define TOTE (NT * EPT)       // 1750000

#define SCAN_B 256
#define SCAN_IPT 4
#define SCAN_CHUNK (SCAN_B * SCAN_IPT)                    // 1024
#define SCAN_NBLK ((NSEG + SCAN_CHUNK - 1) / SCAN_CHUNK)  // 684

typedef __attribute__((ext_vector_type(8))) short bf16x8;
typedef __attribute__((ext_vector_type(4))) float f32x4;

__device__ inline float b2f(unsigned int u16) {
    union { unsigned int i; float f; } v; v.i = u16 << 16; return v.f;
}
__device__ inline unsigned short f2b(float f) {
    union { float f; unsigned int i; } v; v.f = f;
    unsigned int r = v.i + 0x7fffu + ((v.i >> 16) & 1u);
    return (unsigned short)(r >> 16);
}
__device__ inline unsigned int pack2(float a, float b) {
    return (unsigned int)f2b(a) | ((unsigned int)f2b(b) << 16);
}

struct EPtrs { const int* e[NT]; };

// ---------------- dtype conversion ----------------

__global__ void convert_x(const float4* __restrict__ x, uint2* __restrict__ xb, int n4) {
    int i = blockIdx.x * blockDim.x + threadIdx.x;
    if (i < n4) {
        float4 v = x[i];
        xb[i] = make_uint2(pack2(v.x, v.y), pack2(v.z, v.w));
    }
}

// WbT[c][tk] = W[tk][c] * 0.125  (fold the /8 average into W; exact pow2 scale)
__global__ void convert_w(const float* __restrict__ W, unsigned short* __restrict__ WbT) {
    int i = blockIdx.x * blockDim.x + threadIdx.x;  // 131072
    int c = i >> 10, tk = i & 1023;
    WbT[i] = f2b(W[tk * 128 + c] * 0.125f);
}

// ---------------- CSR build ----------------

__global__ void count_all(EPtrs ep, int* __restrict__ cnt) {
    int i = blockIdx.x * blockDim.x + threadIdx.x;
    int t = blockIdx.y;
    if (i < EPT) {
        int dst = ep.e[t][EPT + i];
        atomicAdd(&cnt[t * N_NODES + dst], 1);
    }
}

__global__ void scan_partials(const int* __restrict__ cnt, int* __restrict__ partials) {
    __shared__ int wsum[4];
    int tid = threadIdx.x;
    int base = blockIdx.x * SCAN_CHUNK + tid * SCAN_IPT;
    int s = 0;
#pragma unroll
    for (int j = 0; j < SCAN_IPT; ++j) {
        int idx = base + j;
        if (idx < NSEG) s += cnt[idx];
    }
    for (int off = 32; off > 0; off >>= 1) s += __shfl_down(s, off);
    if ((tid & 63) == 0) wsum[tid >> 6] = s;
    __syncthreads();
    if (tid == 0) partials[blockIdx.x] = wsum[0] + wsum[1] + wsum[2] + wsum[3];
}

__global__ void scan_block(int* partials, int nb) {
    __shared__ int sh[1024];
    int tid = threadIdx.x;
    int v = (tid < nb) ? partials[tid] : 0;
    sh[tid] = v;
    __syncthreads();
    for (int off = 1; off < 1024; off <<= 1) {
        int a = (tid >= off) ? sh[tid - off] : 0;
        __syncthreads();
        sh[tid] += a;
        __syncthreads();
    }
    if (tid < nb) partials[tid] = sh[tid] - v;  // exclusive
}

__global__ void scan_write(const int* __restrict__ cnt, const int* __restrict__ partials,
                           int* __restrict__ scanbuf, int* __restrict__ cursor) {
    __shared__ int wsum[4];
    int tid = threadIdx.x;
    int base = blockIdx.x * SCAN_CHUNK + tid * SCAN_IPT;
    int v[SCAN_IPT];
    int tsum = 0;
#pragma unroll
    for (int j = 0; j < SCAN_IPT; ++j) {
        int idx = base + j;
        v[j] = (idx < NSEG) ? cnt[idx] : 0;
        tsum += v[j];
    }
    int lane = tid & 63, wid = tid >> 6;
    int inc = tsum;
    for (int d = 1; d < 64; d <<= 1) {
        int o = __shfl_up(inc, d);
        if (lane >= d) inc += o;
    }
    if (lane == 63) wsum[wid] = inc;
    __syncthreads();
    int woff = 0;
    for (int w = 0; w < wid; ++w) woff += wsum[w];
    int exc = woff + inc - tsum + partials[blockIdx.x];
#pragma unroll
    for (int j = 0; j < SCAN_IPT; ++j) {
        int idx = base + j;
        if (idx < NSEG) { scanbuf[idx] = exc; cursor[idx] = exc; }
        exc += v[j];
    }
}

__global__ void fill_all(EPtrs ep, int* __restrict__ cursor, int* __restrict__ esrc) {
    int i = blockIdx.x * blockDim.x + threadIdx.x;
    int t = blockIdx.y;
    if (i < EPT) {
        int src = ep.e[t][i];
        int dst = ep.e[t][EPT + i];
        int pos = atomicAdd(&cursor[t * N_NODES + dst], 1);
        esrc[pos] = src;
    }
}

// ---------------- fused aggregate + GEMM ----------------
// block = 512 threads (8 waves), tile = 32 nodes.
// Phase 1: each wave aggregates 4 nodes (all 7 type-means + global mean) into
//          LDS A-tile [32][1024] bf16, XOR-swizzled.
// Phase 2: MFMA A-tile @ WbT -> out[32][128] (scale already folded into WbT).

__global__ __launch_bounds__(512, 4) void fused_agg_gemm(const unsigned short* __restrict__ xb,
                                                         const int* __restrict__ scanbuf,
                                                         const int* __restrict__ cnt,
                                                         const int* __restrict__ esrc,
                                                         const unsigned short* __restrict__ WbT,
                                                         float* __restrict__ out) {
    __shared__ char lds[32 * 2048];  // 64 KB: [32 rows][1024 bf16], swizzled

    int tid = threadIdx.x;
    int wv = tid >> 6, lane = tid & 63;
    int tile0 = blockIdx.x * 32;

    // ---- phase 1: aggregation ----
    const unsigned int* xr = (const unsigned int*)xb;  // bf16 pairs; row = 64 uints
    for (int q = 0; q < 4; ++q) {
        int nloc = wv * 4 + q;
        int n = tile0 + nloc;
        char* rowp = lds + nloc * 2048;
        int rsw = (nloc & 7) << 4;
        if (n < N_NODES) {
            int ss[NT], cc[NT];
#pragma unroll
            for (int t = 0; t < NT; ++t) {
                int seg = t * N_NODES + n;
                ss[t] = scanbuf[seg];
                cc[t] = cnt[seg];
            }
            float a0[NT], a1[NT];
#pragma unroll
            for (int t = 0; t < NT; ++t) {
                int s = ss[t], c = cc[t];
                float s0 = 0.f, s1 = 0.f;
                if (c > 0) {
                    int i0 = esrc[s];
                    int i1 = (c > 1) ? esrc[s + 1] : i0;
                    int i2 = (c > 2) ? esrc[s + 2] : i0;
                    int i3 = (c > 3) ? esrc[s + 3] : i0;
                    unsigned int v0 = xr[(size_t)i0 * 64 + lane];
                    unsigned int v1 = xr[(size_t)i1 * 64 + lane];
                    unsigned int v2 = xr[(size_t)i2 * 64 + lane];
                    unsigned int v3 = xr[(size_t)i3 * 64 + lane];
                    s0 += b2f(v0 & 0xffffu);            s1 += b2f(v0 >> 16);
                    if (c > 1) { s0 += b2f(v1 & 0xffffu); s1 += b2f(v1 >> 16); }
                    if (c > 2) { s0 += b2f(v2 & 0xffffu); s1 += b2f(v2 >> 16); }
                    if (c > 3) { s0 += b2f(v3 & 0xffffu); s1 += b2f(v3 >> 16); }
                    for (int j = 4; j < c; ++j) {
                        unsigned int v = xr[(size_t)esrc[s + j] * 64 + lane];
                        s0 += b2f(v & 0xffffu); s1 += b2f(v >> 16);
                    }
                }
                a0[t] = s0; a1[t] = s1;
            }
            float g0 = 0.f, g1 = 0.f;
            int total = 0;
#pragma unroll
            for (int t = 0; t < NT; ++t) {
                int c = cc[t];
                total += c;
                float inv = 1.0f / (float)(c > 0 ? c : 1);
                int byte = (t * 256 + lane * 4) ^ rsw;
                *(unsigned int*)(rowp + byte) = pack2(a0[t] * inv, a1[t] * inv);
                g0 += a0[t]; g1 += a1[t];
            }
            float gi = 1.0f / (float)(total > 0 ? total : 1);
            int byte = (NT * 256 + lane * 4) ^ rsw;
            *(unsigned int*)(rowp + byte) = pack2(g0 * gi, g1 * gi);
        } else {
            // zero the row so MFMA reads are harmless
#pragma unroll
            for (int t = 0; t < 8; ++t) {
                int byte = (t * 256 + lane * 4) ^ rsw;
                *(unsigned int*)(rowp + byte) = 0u;
            }
        }
    }

    __syncthreads();

    // ---- phase 2: GEMM ----
    int lr = lane & 15, lk = lane >> 4;
    int rowblk = wv & 1;         // 0/1 -> rows 0-15 / 16-31
    int colblk = wv >> 1;        // 0..3 -> cols colblk*32 .. +32
    int row = rowblk * 16 + lr;
    int rxor = (row & 7) << 4;

    f32x4 acc[2];
    acc[0] = (f32x4){0.f, 0.f, 0.f, 0.f};
    acc[1] = (f32x4){0.f, 0.f, 0.f, 0.f};

    const unsigned short* wb0 = WbT + (size_t)(colblk * 32 + lr) * 1024;
    const unsigned short* wb1 = wb0 + 16 * 1024;

#pragma unroll 4
    for (int k0 = 0; k0 < 1024; k0 += 32) {
        int byte = (row * 2048 + (k0 + lk * 8) * 2) ^ rxor;
        bf16x8 fa = *(const bf16x8*)(lds + byte);
        bf16x8 fb0 = *(const bf16x8*)(wb0 + k0 + lk * 8);
        bf16x8 fb1 = *(const bf16x8*)(wb1 + k0 + lk * 8);
        acc[0] = __builtin_amdgcn_mfma_f32_16x16x32_bf16(fa, fb0, acc[0], 0, 0, 0);
        acc[1] = __builtin_amdgcn_mfma_f32_16x16x32_bf16(fa, fb1, acc[1], 0, 0, 0);
    }

#pragma unroll
    for (int tc = 0; tc < 2; ++tc)
#pragma unroll
        for (int q = 0; q < 4; ++q) {
            int n = tile0 + rowblk * 16 + lk * 4 + q;
            if (n < N_NODES)
                out[(size_t)n * 128 + colblk * 32 + tc * 16 + lr] = acc[tc][q];
        }
}

// ---------------- launch ----------------

extern "C" void kernel_launch(void* const* d_in, const int* in_sizes, int n_in,
                              void* d_out, int out_size, void* d_ws, size_t ws_size,
                              hipStream_t stream) {
    const float* x = (const float*)d_in[0];
    const float* W = (const float*)d_in[1];
    EPtrs ep;
    for (int t = 0; t < NT; ++t) ep.e[t] = (const int*)d_in[2 + t];
    float* out = (float*)d_out;

    char* ws = (char*)d_ws;
    int* cnt            = (int*)(ws + 0);                    // 2,800,000
    int* scanbuf        = (int*)(ws + 2800000);              // 2,800,000
    int* cursor         = (int*)(ws + 5600000);              // 2,800,000
    int* partials       = (int*)(ws + 8400000);              // 4,096
    unsigned short* WbT = (unsigned short*)(ws + 8404096);   // 262,144
    int* esrc           = (int*)(ws + 8666240);              // 7,000,000
    unsigned short* xb  = (unsigned short*)(ws + 15666240);  // 25,600,000

    hipMemsetAsync(cnt, 0, NSEG * sizeof(int), stream);

    convert_x<<<(N_NODES * D / 4 + 255) / 256, 256, 0, stream>>>((const float4*)x, (uint2*)xb, N_NODES * D / 4);
    convert_w<<<(1024 * 128 + 255) / 256, 256, 0, stream>>>(W, WbT);

    dim3 egrid((EPT + 255) / 256, NT);
    count_all<<<egrid, 256, 0, stream>>>(ep, cnt);

    scan_partials<<<SCAN_NBLK, SCAN_B, 0, stream>>>(cnt, partials);
    scan_block<<<1, 1024, 0, stream>>>(partials, SCAN_NBLK);
    scan_write<<<SCAN_NBLK, SCAN_B, 0, stream>>>(cnt, partials, scanbuf, cursor);

    fill_all<<<egrid, 256, 0, stream>>>(ep, cursor, esrc);

    int nblocks = (N_NODES + 31) / 32;  // 3125
    fused_agg_gemm<<<nblocks, 512, 0, stream>>>(xb, scanbuf, cnt, esrc, WbT, out);
}

// Round 4
// 521.530 us; speedup vs baseline: 1.1868x; 1.1868x over previous
//
#include <hip/hip_runtime.h>
#include <hip/hip_bf16.h>

#define N_NODES 100000
#define D 128
#define EPT 250000
#define NT 7
#define NSEG (NT * N_NODES)   // 700000
#define TOTE (NT * EPT)       // 1750000

#define SCAN_B 256
#define SCAN_IPT 4
#define SCAN_CHUNK (SCAN_B * SCAN_IPT)                    // 1024
#define SCAN_NBLK ((NSEG + SCAN_CHUNK - 1) / SCAN_CHUNK)  // 684

typedef __attribute__((ext_vector_type(8))) short bf16x8;
typedef __attribute__((ext_vector_type(4))) float f32x4;

__device__ inline float b2f(unsigned int u16) {
    union { unsigned int i; float f; } v; v.i = u16 << 16; return v.f;
}
__device__ inline unsigned short f2b(float f) {
    union { float f; unsigned int i; } v; v.f = f;
    unsigned int r = v.i + 0x7fffu + ((v.i >> 16) & 1u);
    return (unsigned short)(r >> 16);
}
__device__ inline unsigned int pack2(float a, float b) {
    return (unsigned int)f2b(a) | ((unsigned int)f2b(b) << 16);
}

struct EPtrs { const int* e[NT]; };

// ---------------- dtype conversion ----------------

__global__ void convert_x(const float4* __restrict__ x, uint2* __restrict__ xb, int n4) {
    int i = blockIdx.x * blockDim.x + threadIdx.x;
    if (i < n4) {
        float4 v = x[i];
        xb[i] = make_uint2(pack2(v.x, v.y), pack2(v.z, v.w));
    }
}

// WbT[c][tk] = W[tk][c] * 0.125  (fold the /8 average into W; exact pow2 scale)
__global__ void convert_w(const float* __restrict__ W, unsigned short* __restrict__ WbT) {
    int i = blockIdx.x * blockDim.x + threadIdx.x;  // 131072
    int c = i >> 10, tk = i & 1023;
    WbT[i] = f2b(W[tk * 128 + c] * 0.125f);
}

// ---------------- CSR build ----------------

__global__ void count_all(EPtrs ep, int* __restrict__ cnt) {
    int i = blockIdx.x * blockDim.x + threadIdx.x;
    int t = blockIdx.y;
    if (i < EPT) {
        int dst = ep.e[t][EPT + i];
        atomicAdd(&cnt[t * N_NODES + dst], 1);
    }
}

__global__ void scan_partials(const int* __restrict__ cnt, int* __restrict__ partials) {
    __shared__ int wsum[4];
    int tid = threadIdx.x;
    int base = blockIdx.x * SCAN_CHUNK + tid * SCAN_IPT;
    int s = 0;
#pragma unroll
    for (int j = 0; j < SCAN_IPT; ++j) {
        int idx = base + j;
        if (idx < NSEG) s += cnt[idx];
    }
    for (int off = 32; off > 0; off >>= 1) s += __shfl_down(s, off);
    if ((tid & 63) == 0) wsum[tid >> 6] = s;
    __syncthreads();
    if (tid == 0) partials[blockIdx.x] = wsum[0] + wsum[1] + wsum[2] + wsum[3];
}

__global__ void scan_block(int* partials, int nb) {
    __shared__ int sh[1024];
    int tid = threadIdx.x;
    int v = (tid < nb) ? partials[tid] : 0;
    sh[tid] = v;
    __syncthreads();
    for (int off = 1; off < 1024; off <<= 1) {
        int a = (tid >= off) ? sh[tid - off] : 0;
        __syncthreads();
        sh[tid] += a;
        __syncthreads();
    }
    if (tid < nb) partials[tid] = sh[tid] - v;  // exclusive
}

__global__ void scan_write(const int* __restrict__ cnt, const int* __restrict__ partials,
                           int* __restrict__ scanbuf, int* __restrict__ cursor) {
    __shared__ int wsum[4];
    int tid = threadIdx.x;
    int base = blockIdx.x * SCAN_CHUNK + tid * SCAN_IPT;
    int v[SCAN_IPT];
    int tsum = 0;
#pragma unroll
    for (int j = 0; j < SCAN_IPT; ++j) {
        int idx = base + j;
        v[j] = (idx < NSEG) ? cnt[idx] : 0;
        tsum += v[j];
    }
    int lane = tid & 63, wid = tid >> 6;
    int inc = tsum;
    for (int d = 1; d < 64; d <<= 1) {
        int o = __shfl_up(inc, d);
        if (lane >= d) inc += o;
    }
    if (lane == 63) wsum[wid] = inc;
    __syncthreads();
    int woff = 0;
    for (int w = 0; w < wid; ++w) woff += wsum[w];
    int exc = woff + inc - tsum + partials[blockIdx.x];
#pragma unroll
    for (int j = 0; j < SCAN_IPT; ++j) {
        int idx = base + j;
        if (idx < NSEG) { scanbuf[idx] = exc; cursor[idx] = exc; }
        exc += v[j];
    }
}

__global__ void fill_all(EPtrs ep, int* __restrict__ cursor, int* __restrict__ esrc) {
    int i = blockIdx.x * blockDim.x + threadIdx.x;
    int t = blockIdx.y;
    if (i < EPT) {
        int src = ep.e[t][i];
        int dst = ep.e[t][EPT + i];
        int pos = atomicAdd(&cursor[t * N_NODES + dst], 1);
        esrc[pos] = src;
    }
}

// ---------------- fused aggregate + GEMM ----------------
// block = 512 threads (8 waves), tile = 16 nodes, LDS 32KB -> 3 blocks/CU.
// Phase 1 : 112 (type,node) segments strided across the 8 waves; per segment
//           the edge list head is fetched as uniform int4 broadcasts, rows
//           gathered with up-to-8 independent loads; mean -> swizzled LDS row.
// Phase 1b: global mean = count-weighted recombination of the 7 type means.
// Phase 2 : MFMA [16][1024] @ WbT -> out (scale folded into WbT).

__global__ __launch_bounds__(512, 6) void fused_agg_gemm(const unsigned short* __restrict__ xb,
                                                         const int* __restrict__ scanbuf,
                                                         const int* __restrict__ cnt,
                                                         const int* __restrict__ esrc,
                                                         const unsigned short* __restrict__ WbT,
                                                         float* __restrict__ out) {
    __shared__ char lds[16 * 2048];  // 32 KB: [16 rows][1024 bf16], XOR-swizzled
    __shared__ int ccsh[16 * 8];

    int tid = threadIdx.x;
    int wv = tid >> 6, lane = tid & 63;
    int tile0 = blockIdx.x * 16;     // N_NODES % 16 == 0, no tail
    const unsigned int* xr = (const unsigned int*)xb;  // bf16 pairs; row = 64 uints

    // ---- phase 1: per-segment means ----
#pragma unroll 2
    for (int sl = wv; sl < 16 * NT; sl += 8) {
        int t = sl >> 4, nloc = sl & 15;
        int n = tile0 + nloc;
        char* rowp = lds + nloc * 2048;
        int dbyte = (t * 256 + lane * 4) ^ ((nloc & 7) << 4);
        int seg = t * N_NODES + n;
        int start = scanbuf[seg];
        int c = cnt[seg];
        if (lane == 0) ccsh[nloc * 8 + t] = c;
        float s0 = 0.f, s1 = 0.f, inv = 1.0f;
        if (c > 0) {
            int4 iv = *(const int4*)(esrc + start);      // uniform broadcast
            int i1 = (c > 1) ? iv.y : iv.x;
            int i2 = (c > 2) ? iv.z : iv.x;
            int i3 = (c > 3) ? iv.w : iv.x;
            unsigned int v0 = xr[(size_t)iv.x * 64 + lane];
            unsigned int v1 = xr[(size_t)i1 * 64 + lane];
            unsigned int v2 = xr[(size_t)i2 * 64 + lane];
            unsigned int v3 = xr[(size_t)i3 * 64 + lane];
            s0 = b2f(v0 & 0xffffu);               s1 = b2f(v0 >> 16);
            if (c > 1) { s0 += b2f(v1 & 0xffffu); s1 += b2f(v1 >> 16); }
            if (c > 2) { s0 += b2f(v2 & 0xffffu); s1 += b2f(v2 >> 16); }
            if (c > 3) { s0 += b2f(v3 & 0xffffu); s1 += b2f(v3 >> 16); }
            if (c > 4) {
                int4 jv = *(const int4*)(esrc + start + 4);
                int i5 = (c > 5) ? jv.y : jv.x;
                int i6 = (c > 6) ? jv.z : jv.x;
                int i7 = (c > 7) ? jv.w : jv.x;
                unsigned int w0 = xr[(size_t)jv.x * 64 + lane];
                unsigned int w1 = xr[(size_t)i5 * 64 + lane];
                unsigned int w2 = xr[(size_t)i6 * 64 + lane];
                unsigned int w3 = xr[(size_t)i7 * 64 + lane];
                s0 += b2f(w0 & 0xffffu);              s1 += b2f(w0 >> 16);
                if (c > 5) { s0 += b2f(w1 & 0xffffu); s1 += b2f(w1 >> 16); }
                if (c > 6) { s0 += b2f(w2 & 0xffffu); s1 += b2f(w2 >> 16); }
                if (c > 7) { s0 += b2f(w3 & 0xffffu); s1 += b2f(w3 >> 16); }
                for (int j = 8; j < c; ++j) {  // P(c>8) ~ 0.1%
                    unsigned int v = xr[(size_t)esrc[start + j] * 64 + lane];
                    s0 += b2f(v & 0xffffu); s1 += b2f(v >> 16);
                }
            }
            inv = 1.0f / (float)c;
        }
        *(unsigned int*)(rowp + dbyte) = pack2(s0 * inv, s1 * inv);
    }
    __syncthreads();

    // ---- phase 1b: global mean from the 7 type means ----
#pragma unroll
    for (int qq = 0; qq < 2; ++qq) {
        int nloc = wv * 2 + qq;
        char* rowp = lds + nloc * 2048;
        int rsw = (nloc & 7) << 4;
        float g0 = 0.f, g1 = 0.f;
        int ctot = 0;
#pragma unroll
        for (int t = 0; t < NT; ++t) {
            int c = ccsh[nloc * 8 + t];
            unsigned int m = *(unsigned int*)(rowp + ((t * 256 + lane * 4) ^ rsw));
            float fc = (float)c;
            ctot += c;
            g0 += fc * b2f(m & 0xffffu);
            g1 += fc * b2f(m >> 16);
        }
        float gi = 1.0f / (float)(ctot > 0 ? ctot : 1);
        *(unsigned int*)(rowp + ((NT * 256 + lane * 4) ^ rsw)) = pack2(g0 * gi, g1 * gi);
    }
    __syncthreads();

    // ---- phase 2: GEMM [16][1024] @ WbT -> out[16][128] ----
    int lr = lane & 15, lk = lane >> 4;
    f32x4 acc = (f32x4){0.f, 0.f, 0.f, 0.f};
    const unsigned short* wb = WbT + (size_t)(wv * 16 + lr) * 1024;
    int rbase = lr * 2048;
    int rxor = (lr & 7) << 4;
#pragma unroll 4
    for (int k0 = 0; k0 < 1024; k0 += 32) {
        bf16x8 fa = *(const bf16x8*)(lds + ((rbase + (k0 + lk * 8) * 2) ^ rxor));
        bf16x8 fb = *(const bf16x8*)(wb + k0 + lk * 8);
        acc = __builtin_amdgcn_mfma_f32_16x16x32_bf16(fa, fb, acc, 0, 0, 0);
    }
    int nb = tile0 + lk * 4;
#pragma unroll
    for (int q = 0; q < 4; ++q)
        out[(size_t)(nb + q) * 128 + wv * 16 + lr] = acc[q];
}

// ---------------- launch ----------------

extern "C" void kernel_launch(void* const* d_in, const int* in_sizes, int n_in,
                              void* d_out, int out_size, void* d_ws, size_t ws_size,
                              hipStream_t stream) {
    const float* x = (const float*)d_in[0];
    const float* W = (const float*)d_in[1];
    EPtrs ep;
    for (int t = 0; t < NT; ++t) ep.e[t] = (const int*)d_in[2 + t];
    float* out = (float*)d_out;

    char* ws = (char*)d_ws;
    int* cnt            = (int*)(ws + 0);                    // 2,800,000
    int* scanbuf        = (int*)(ws + 2800000);              // 2,800,000
    int* cursor         = (int*)(ws + 5600000);              // 2,800,000
    int* partials       = (int*)(ws + 8400000);              // 4,096
    unsigned short* WbT = (unsigned short*)(ws + 8404096);   // 262,144
    int* esrc           = (int*)(ws + 8666240);              // 7,000,000 + 64 pad
    unsigned short* xb  = (unsigned short*)(ws + 15666432);  // 25,600,000

    hipMemsetAsync(cnt, 0, NSEG * sizeof(int), stream);

    convert_x<<<(N_NODES * D / 4 + 255) / 256, 256, 0, stream>>>((const float4*)x, (uint2*)xb, N_NODES * D / 4);
    convert_w<<<(1024 * 128 + 255) / 256, 256, 0, stream>>>(W, WbT);

    dim3 egrid((EPT + 255) / 256, NT);
    count_all<<<egrid, 256, 0, stream>>>(ep, cnt);

    scan_partials<<<SCAN_NBLK, SCAN_B, 0, stream>>>(cnt, partials);
    scan_block<<<1, 1024, 0, stream>>>(partials, SCAN_NBLK);
    scan_write<<<SCAN_NBLK, SCAN_B, 0, stream>>>(cnt, partials, scanbuf, cursor);

    fill_all<<<egrid, 256, 0, stream>>>(ep, cursor, esrc);

    int nblocks = N_NODES / 16;  // 6250, exact
    fused_agg_gemm<<<nblocks, 512, 0, stream>>>(xb, scanbuf, cnt, esrc, WbT, out);
}

// Round 5
// 380.116 us; speedup vs baseline: 1.6283x; 1.3720x over previous
//
#include <hip/hip_runtime.h>
#include <hip/hip_bf16.h>

#define N_NODES 100000
#define D 128
#define EPT 250000
#define NT 7
#define NSEG (NT * N_NODES)   // 700000
#define TOTE (NT * EPT)       // 1750000

#define SCAN_B 256
#define SCAN_IPT 4
#define SCAN_CHUNK (SCAN_B * SCAN_IPT)                    // 1024
#define SCAN_NBLK ((NSEG + SCAN_CHUNK - 1) / SCAN_CHUNK)  // 684

#define CVX_BLOCKS 12500   // 3,200,000 float4 / 256 (exact)
#define CVW_BLOCKS 512     // 131,072 / 256 (exact)
#define CNT_BLOCKS 977     // ceil(250000/256)

typedef __attribute__((ext_vector_type(8))) short bf16x8;
typedef __attribute__((ext_vector_type(4))) float f32x4;

__device__ inline float b2f(unsigned int u16) {
    union { unsigned int i; float f; } v; v.i = u16 << 16; return v.f;
}
__device__ inline unsigned short f2b(float f) {
    union { float f; unsigned int i; } v; v.f = f;
    unsigned int r = v.i + 0x7fffu + ((v.i >> 16) & 1u);
    return (unsigned short)(r >> 16);
}
__device__ inline unsigned int pack2(float a, float b) {
    return (unsigned int)f2b(a) | ((unsigned int)f2b(b) << 16);
}

struct EPtrs { const int* e[NT]; };

// ---------------- merged prep: convert_x | convert_w | count_all ----------------

__global__ __launch_bounds__(256) void prep(const float4* __restrict__ x, uint2* __restrict__ xb,
                                            const float* __restrict__ W, unsigned short* __restrict__ WbT,
                                            EPtrs ep, int* __restrict__ cnt) {
    int b = blockIdx.x, tid = threadIdx.x;
    if (b < CVX_BLOCKS) {
        int i = b * 256 + tid;               // < 3,200,000 exact
        float4 v = x[i];
        xb[i] = make_uint2(pack2(v.x, v.y), pack2(v.z, v.w));
    } else if (b < CVX_BLOCKS + CVW_BLOCKS) {
        int i = (b - CVX_BLOCKS) * 256 + tid;  // < 131072 exact
        int c = i >> 10, tk = i & 1023;
        WbT[i] = f2b(W[tk * 128 + c] * 0.125f);  // fold /8 (exact pow2)
    } else {
        int r = b - CVX_BLOCKS - CVW_BLOCKS;
        int t = r / CNT_BLOCKS;
        int i = (r % CNT_BLOCKS) * 256 + tid;
        if (i < EPT) atomicAdd(&cnt[t * N_NODES + ep.e[t][EPT + i]], 1);
    }
}

// ---------------- CSR scan (proven, unchanged) ----------------

__global__ void scan_partials(const int* __restrict__ cnt, int* __restrict__ partials) {
    __shared__ int wsum[4];
    int tid = threadIdx.x;
    int base = blockIdx.x * SCAN_CHUNK + tid * SCAN_IPT;
    int s = 0;
#pragma unroll
    for (int j = 0; j < SCAN_IPT; ++j) {
        int idx = base + j;
        if (idx < NSEG) s += cnt[idx];
    }
    for (int off = 32; off > 0; off >>= 1) s += __shfl_down(s, off);
    if ((tid & 63) == 0) wsum[tid >> 6] = s;
    __syncthreads();
    if (tid == 0) partials[blockIdx.x] = wsum[0] + wsum[1] + wsum[2] + wsum[3];
}

__global__ void scan_block(int* partials, int nb) {
    __shared__ int sh[1024];
    int tid = threadIdx.x;
    int v = (tid < nb) ? partials[tid] : 0;
    sh[tid] = v;
    __syncthreads();
    for (int off = 1; off < 1024; off <<= 1) {
        int a = (tid >= off) ? sh[tid - off] : 0;
        __syncthreads();
        sh[tid] += a;
        __syncthreads();
    }
    if (tid < nb) partials[tid] = sh[tid] - v;  // exclusive
}

__global__ void scan_write(const int* __restrict__ cnt, const int* __restrict__ partials,
                           int* __restrict__ scanbuf, int* __restrict__ cursor) {
    __shared__ int wsum[4];
    int tid = threadIdx.x;
    int base = blockIdx.x * SCAN_CHUNK + tid * SCAN_IPT;
    int v[SCAN_IPT];
    int tsum = 0;
#pragma unroll
    for (int j = 0; j < SCAN_IPT; ++j) {
        int idx = base + j;
        v[j] = (idx < NSEG) ? cnt[idx] : 0;
        tsum += v[j];
    }
    int lane = tid & 63, wid = tid >> 6;
    int inc = tsum;
    for (int d = 1; d < 64; d <<= 1) {
        int o = __shfl_up(inc, d);
        if (lane >= d) inc += o;
    }
    if (lane == 63) wsum[wid] = inc;
    __syncthreads();
    int woff = 0;
    for (int w = 0; w < wid; ++w) woff += wsum[w];
    int exc = woff + inc - tsum + partials[blockIdx.x];
#pragma unroll
    for (int j = 0; j < SCAN_IPT; ++j) {
        int idx = base + j;
        if (idx < NSEG) { scanbuf[idx] = exc; cursor[idx] = exc; }
        exc += v[j];
    }
}

__global__ void fill_all(EPtrs ep, int* __restrict__ cursor, int* __restrict__ esrc) {
    int i = blockIdx.x * blockDim.x + threadIdx.x;
    int t = blockIdx.y;
    if (i < EPT) {
        int src = ep.e[t][i];
        int dst = ep.e[t][EPT + i];
        int pos = atomicAdd(&cursor[t * N_NODES + dst], 1);
        esrc[pos] = src;
    }
}

// ---------------- fused aggregate + GEMM ----------------
// block = 512 threads (8 waves), tile = 32 nodes (N_NODES = 32*3125 exact),
// LDS 64 KB -> 2 blocks/CU.
// Phase 1: wave handles 4 nodes. Per node: 7 scalar (start,count) loads, 7
//          uniform int4 head loads, then up to 28 INDEPENDENT clamped gathers
//          in one branchless block (saddr form: readfirstlane'd index + lane
//          offset). Rare tails (c>4) in a second pass. Global row = sum of
//          the 7 type sums (in-register, no LDS round trip).
// Phase 2: wave computes 32 rows x 16 cols via 2 MFMA accumulators.

__global__ __launch_bounds__(512, 4) void fused_agg_gemm(const unsigned short* __restrict__ xb,
                                                         const int* __restrict__ scanbuf,
                                                         const int* __restrict__ cnt,
                                                         const int* __restrict__ esrc,
                                                         const unsigned short* __restrict__ WbT,
                                                         float* __restrict__ out) {
    __shared__ char lds[32 * 2048];  // 64 KB: [32 rows][1024 bf16], XOR-swizzled

    int tid = threadIdx.x;
    int wvu = __builtin_amdgcn_readfirstlane(tid >> 6);
    int lane = tid & 63;
    int tile0 = blockIdx.x * 32;
    const unsigned int* xr = (const unsigned int*)xb;  // bf16 pairs; row = 64 uints

    // ---- phase 1 ----
    for (int q = 0; q < 4; ++q) {
        int nloc = wvu * 4 + q;
        int n = tile0 + nloc;
        char* rowp = lds + nloc * 2048;
        int rsw = (nloc & 7) << 4;

        int st[NT], ct[NT];
#pragma unroll
        for (int t = 0; t < NT; ++t) {
            st[t] = scanbuf[t * N_NODES + n];
            ct[t] = cnt[t * N_NODES + n];
        }

        float s0a[NT], s1a[NT];
        // main: first 4 edges of every type, fully branchless -> max MLP
#pragma unroll
        for (int t = 0; t < NT; ++t) {
            int c = ct[t];
            int4 h = *(const int4*)(esrc + st[t]);  // uniform broadcast (padded)
            int i0 = (c > 0) ? __builtin_amdgcn_readfirstlane(h.x) : 0;
            int i1 = (c > 1) ? __builtin_amdgcn_readfirstlane(h.y) : i0;
            int i2 = (c > 2) ? __builtin_amdgcn_readfirstlane(h.z) : i0;
            int i3 = (c > 3) ? __builtin_amdgcn_readfirstlane(h.w) : i0;
            unsigned int v0 = (xr + ((size_t)i0 << 6))[lane];
            unsigned int v1 = (xr + ((size_t)i1 << 6))[lane];
            unsigned int v2 = (xr + ((size_t)i2 << 6))[lane];
            unsigned int v3 = (xr + ((size_t)i3 << 6))[lane];
            float s0 = (c > 0) ? b2f(v0 & 0xffffu) : 0.f;
            float s1 = (c > 0) ? b2f(v0 >> 16) : 0.f;
            s0 += (c > 1) ? b2f(v1 & 0xffffu) : 0.f;
            s1 += (c > 1) ? b2f(v1 >> 16) : 0.f;
            s0 += (c > 2) ? b2f(v2 & 0xffffu) : 0.f;
            s1 += (c > 2) ? b2f(v2 >> 16) : 0.f;
            s0 += (c > 3) ? b2f(v3 & 0xffffu) : 0.f;
            s1 += (c > 3) ? b2f(v3 >> 16) : 0.f;
            s0a[t] = s0; s1a[t] = s1;
        }
        // tails (P(c>4) ~ 11% per segment)
#pragma unroll
        for (int t = 0; t < NT; ++t) {
            int c = ct[t];
            if (c > 4) {
                int4 h = *(const int4*)(esrc + st[t] + 4);
                int i4 = __builtin_amdgcn_readfirstlane(h.x);
                int i5 = (c > 5) ? __builtin_amdgcn_readfirstlane(h.y) : i4;
                int i6 = (c > 6) ? __builtin_amdgcn_readfirstlane(h.z) : i4;
                int i7 = (c > 7) ? __builtin_amdgcn_readfirstlane(h.w) : i4;
                unsigned int v4 = (xr + ((size_t)i4 << 6))[lane];
                unsigned int v5 = (xr + ((size_t)i5 << 6))[lane];
                unsigned int v6 = (xr + ((size_t)i6 << 6))[lane];
                unsigned int v7 = (xr + ((size_t)i7 << 6))[lane];
                float s0 = b2f(v4 & 0xffffu);
                float s1 = b2f(v4 >> 16);
                s0 += (c > 5) ? b2f(v5 & 0xffffu) : 0.f;
                s1 += (c > 5) ? b2f(v5 >> 16) : 0.f;
                s0 += (c > 6) ? b2f(v6 & 0xffffu) : 0.f;
                s1 += (c > 6) ? b2f(v6 >> 16) : 0.f;
                s0 += (c > 7) ? b2f(v7 & 0xffffu) : 0.f;
                s1 += (c > 7) ? b2f(v7 >> 16) : 0.f;
                for (int j = 8; j < c; ++j) {  // P ~ 0.2%
                    int ij = __builtin_amdgcn_readfirstlane(esrc[st[t] + j]);
                    unsigned int v = (xr + ((size_t)ij << 6))[lane];
                    s0 += b2f(v & 0xffffu);
                    s1 += b2f(v >> 16);
                }
                s0a[t] += s0; s1a[t] += s1;
            }
        }
        // write type means + global mean (recombined in-register, exact sums)
        float g0 = 0.f, g1 = 0.f;
        int ctot = 0;
#pragma unroll
        for (int t = 0; t < NT; ++t) {
            int c = ct[t];
            ctot += c;
            g0 += s0a[t]; g1 += s1a[t];
            float inv = 1.0f / (float)(c > 0 ? c : 1);
            *(unsigned int*)(rowp + ((t * 256 + lane * 4) ^ rsw)) = pack2(s0a[t] * inv, s1a[t] * inv);
        }
        float gi = 1.0f / (float)(ctot > 0 ? ctot : 1);
        *(unsigned int*)(rowp + ((NT * 256 + lane * 4) ^ rsw)) = pack2(g0 * gi, g1 * gi);
    }
    __syncthreads();

    // ---- phase 2: GEMM [32][1024] @ WbT -> out[32][128] ----
    int lr = lane & 15, lk = lane >> 4;
    f32x4 acc0 = (f32x4){0.f, 0.f, 0.f, 0.f};
    f32x4 acc1 = (f32x4){0.f, 0.f, 0.f, 0.f};
    const unsigned short* wb = WbT + (size_t)(wvu * 16 + lr) * 1024;
    int rx = (lr & 7) << 4;  // rows r and r+16 share (r&7) -> same XOR

#pragma unroll 4
    for (int k0 = 0; k0 < 1024; k0 += 32) {
        int koff = (k0 + lk * 8) * 2;
        bf16x8 fa0 = *(const bf16x8*)(lds + ((lr * 2048 + koff) ^ rx));
        bf16x8 fa1 = *(const bf16x8*)(lds + (((lr + 16) * 2048 + koff) ^ rx));
        bf16x8 fb = *(const bf16x8*)(wb + k0 + lk * 8);
        acc0 = __builtin_amdgcn_mfma_f32_16x16x32_bf16(fa0, fb, acc0, 0, 0, 0);
        acc1 = __builtin_amdgcn_mfma_f32_16x16x32_bf16(fa1, fb, acc1, 0, 0, 0);
    }

    int col = wvu * 16 + lr;
    int n0 = tile0 + lk * 4;
#pragma unroll
    for (int qq = 0; qq < 4; ++qq) {
        out[(size_t)(n0 + qq) * 128 + col] = acc0[qq];
        out[(size_t)(n0 + 16 + qq) * 128 + col] = acc1[qq];
    }
}

// ---------------- launch ----------------

extern "C" void kernel_launch(void* const* d_in, const int* in_sizes, int n_in,
                              void* d_out, int out_size, void* d_ws, size_t ws_size,
                              hipStream_t stream) {
    const float* x = (const float*)d_in[0];
    const float* W = (const float*)d_in[1];
    EPtrs ep;
    for (int t = 0; t < NT; ++t) ep.e[t] = (const int*)d_in[2 + t];
    float* out = (float*)d_out;

    char* ws = (char*)d_ws;
    int* cnt            = (int*)(ws + 0);                    // 2,800,000
    int* scanbuf        = (int*)(ws + 2800000);              // 2,800,000
    int* cursor         = (int*)(ws + 5600000);              // 2,800,000
    int* partials       = (int*)(ws + 8400000);              // 4,096
    unsigned short* WbT = (unsigned short*)(ws + 8404096);   // 262,144
    int* esrc           = (int*)(ws + 8666240);              // 7,000,000 + 192 pad
    unsigned short* xb  = (unsigned short*)(ws + 15666432);  // 25,600,000

    hipMemsetAsync(cnt, 0, NSEG * sizeof(int), stream);

    int prep_blocks = CVX_BLOCKS + CVW_BLOCKS + CNT_BLOCKS * NT;  // 19851
    prep<<<prep_blocks, 256, 0, stream>>>((const float4*)x, (uint2*)xb, W, WbT, ep, cnt);

    scan_partials<<<SCAN_NBLK, SCAN_B, 0, stream>>>(cnt, partials);
    scan_block<<<1, 1024, 0, stream>>>(partials, SCAN_NBLK);
    scan_write<<<SCAN_NBLK, SCAN_B, 0, stream>>>(cnt, partials, scanbuf, cursor);

    dim3 egrid(CNT_BLOCKS, NT);
    fill_all<<<egrid, 256, 0, stream>>>(ep, cursor, esrc);

    int nblocks = N_NODES / 32;  // 3125, exact
    fused_agg_gemm<<<nblocks, 512, 0, stream>>>(xb, scanbuf, cnt, esrc, WbT, out);
}